// Round 10
// baseline (424.503 us; speedup 1.0000x reference)
//
#include <hip/hip_runtime.h>

// iRPE contextual/transposed PRODUCT, round-14b: DRAIN-THEN-SPIN PROBE
// (identical resubmit of r14 -- the round-9 bench died on a container
// failure before running; no data was produced, so the probe stands).
//
// r12/r13: zero-wait structure is best (286.3us) and TLP-flat. Ambiguity:
// the 1 GiB poison fill is 4x the output size, so the harness may ALSO
// re-poison out (268MB ~= 42us, invisible below top-5). Two live models:
//   A: overhead ~157us -> kernel ~130us = 2.2 TB/s (3x off roofline)
//   B: overhead ~222us -> kernel  ~64us = 4.3 TB/s (near roofline)
// This probe: EXACT r12 kernel + (1) s_waitcnt vmcnt(0) after stores (the
// store drain is now INSIDE the timed region, unlike r10's fire-and-forget
// confound) + (2) ~136-170us calibrated FMA spin to lift the row above the
// fills. Self-calibrating: T_store ~= (1 - VALUBusy) * row_dur.
// Pre-committed: T>=110us -> Model A, ship r12 + declare ceiling.
//                T~=45-75 -> Model B, ship r12 + declare (fills dominate).
//                75-110   -> one store-burst restructure left.

constexpr int cL = 1024;
constexpr int cD = 64;
constexpr int cK = 49;
constexpr int cRW = 32;   // rows per wave

typedef float vf4 __attribute__((ext_vector_type(4)));

// piecewise_index(d) + BETA_INT for this config (verified absmax 0.0)
__device__ __forceinline__ int bucket_c(int d) {
    int a = d < 0 ? -d : d;
    int m = a < 4 ? a : 4;     // min(|d|,4)
    m -= (m >= 3) ? 1 : 0;     // q(|d|) = {0,1,2,2,3,3,...}
    int p = d < 0 ? -m : m;
    return p + 3;
}

__global__ __launch_bounds__(256) void irpe_probe(
    const float* __restrict__ x,   // (bh, i, d)
    const float* __restrict__ W,   // (h, d, k)
    float*       __restrict__ out) // (bh, i, j)
{
    __shared__ float xw[4][cRW * cD];    // 4 waves x 8 KB, wave-private

    const int gid  = blockIdx.x;         // 512 blocks = 2/CU
    const int bh   = gid & 63;
    const int segq = gid >> 6;           // 0..7
    const int tid  = threadIdx.x;
    const int w    = tid >> 6;           // wave 0..3
    const int lane = tid & 63;
    const int i0w  = segq * 128 + w * cRW;
    const int h    = bh & 7;

    // ---- one-time: this lane's W column into registers ----
    const int klane = lane < cK ? lane : lane - cK;
    float wreg[cD];
    const float* wcol = W + (size_t)h * cD * cK + klane;
    #pragma unroll
    for (int d = 0; d < cD; ++d) wreg[d] = wcol[(size_t)d * cK];

    // ---- one-time: stage this wave's 32 x-rows into its LDS region ----
    vf4*       xw4  = (vf4*)xw[w];
    const vf4* xsrc = (const vf4*)(x + ((size_t)bh * cL + i0w) * cD);
    #pragma unroll
    for (int r = 0; r < 8; ++r) xw4[r * 64 + lane] = xsrc[r * 64 + lane];

    const int xj = (lane * 4) & 31;
    const int l8 = lane >> 3;

    const float* xrow  = xw[w];
    vf4*         obase = (vf4*)(out + ((size_t)bh * cL + i0w) * cL);

    float seed = 0.0f;
    for (int rp = 0; rp < cRW; rp += 2) {
        float a0 = 0.0f, a1 = 0.0f;
        const vf4* xr0 = (const vf4*)(xrow + (rp + 0) * cD);
        const vf4* xr1 = (const vf4*)(xrow + (rp + 1) * cD);
        #pragma unroll
        for (int dq = 0; dq < cD / 4; ++dq) {
            vf4 v0 = xr0[dq];
            vf4 v1 = xr1[dq];
            #pragma unroll
            for (int u = 0; u < 4; ++u) {
                a0 = fmaf(v0[u], wreg[dq * 4 + u], a0);
                a1 = fmaf(v1[u], wreg[dq * 4 + u], a1);
            }
        }
        seed += a0 + a1;
        #pragma unroll
        for (int rr = 0; rr < 2; ++rr) {
            const int   i   = i0w + rp + rr;
            const float acc = rr ? a1 : a0;
            const int   yi  = i >> 5;
            const int   xi  = i & 31;
            const int   bse = xi - xj;
            int cb[4];
            #pragma unroll
            for (int cc = 0; cc < 4; ++cc) cb[cc] = bucket_c(bse - cc);
            #pragma unroll
            for (int s = 0; s < 4; ++s) {
                const int rb = 7 * bucket_c(yi - (s * 8 + l8));
                vf4 o;
                o.x = __shfl(acc, rb + cb[0], 64);
                o.y = __shfl(acc, rb + cb[1], 64);
                o.z = __shfl(acc, rb + cb[2], 64);
                o.w = __shfl(acc, rb + cb[3], 64);
                obase[(size_t)(rp + rr) * (cL / 4) + s * 64 + lane] = o;
            }
        }
    }

    // ---- PROBE 1: wait for ALL stores to reach memory (inside timing) ----
    asm volatile("s_waitcnt vmcnt(0)" ::: "memory");

    // ---- PROBE 2: calibrated spin to surface the row above the fills ----
    // 1280 iters x 64 fma = 81920 fma/thread; 2 waves/SIMD serial ->
    // 81920*2*2 = 327K SIMD-cyc ~= 136us @2.4GHz .. 170us @1.93GHz.
    float b0 = seed + 1.0f;
    float b1 = b0 * 1.125f,  b2 = b0 * 1.25f,  b3 = b0 * 1.375f;
    float b4 = b0 * 1.5f,    b5 = b0 * 1.625f, b6 = b0 * 1.75f, b7 = b0 * 1.875f;
    for (int s2 = 0; s2 < 1280; ++s2) {
        #pragma unroll
        for (int u = 0; u < 8; ++u) {
            b0 = fmaf(b0, 1.0000001f, 0.0625f);
            b1 = fmaf(b1, 1.0000002f, 0.0625f);
            b2 = fmaf(b2, 1.0000003f, 0.0625f);
            b3 = fmaf(b3, 1.0000004f, 0.0625f);
            b4 = fmaf(b4, 1.0000005f, 0.0625f);
            b5 = fmaf(b5, 1.0000006f, 0.0625f);
            b6 = fmaf(b6, 1.0000007f, 0.0625f);
            b7 = fmaf(b7, 1.0000008f, 0.0625f);
        }
    }
    asm volatile("" :: "v"(b0), "v"(b1), "v"(b2), "v"(b3),
                       "v"(b4), "v"(b5), "v"(b6), "v"(b7));
}

extern "C" void kernel_launch(void* const* d_in, const int* in_sizes, int n_in,
                              void* d_out, int out_size, void* d_ws, size_t ws_size,
                              hipStream_t stream) {
    const float* x   = (const float*)d_in[0];   // (8,8,1024,64) fp32
    const float* W   = (const float*)d_in[1];   // (8,64,49) fp32
    float*       out = (float*)d_out;           // (8,8,1024,1024) fp32

    const int grid = 64 * 8;                    // 512 blocks, 2 per CU
    irpe_probe<<<grid, 256, 0, stream>>>(x, W, out);
}

// Round 11
// 285.494 us; speedup vs baseline: 1.4869x; 1.4869x over previous
//
#include <hip/hip_runtime.h>

// iRPE contextual/transposed PRODUCT — FINAL (r12 zero-wait wave streaming).
//
//   lt[bh,i,k] = sum_d x[bh,i,d] * W[h,d,k]    (K=49 GEMV, lane k holds col)
//   out[bh,i,j] = lt[bh,i, bucket(i,j)]         (256 MiB stream)
//
// Evidence trail (r10/r11/r14b direct counters):
//  - WRITE_SIZE = 262144 KB exact, FETCH = 8.3 MB: no RFO, no over-fetch.
//  - r14b drain-probe (s_waitcnt vmcnt(0) + calibrated spin, VALUBusy 74.2%
//    @ 228us): exposed store-drain ~57us for 268 MB = ~4.7 TB/s, ~74% of
//    the poison-fill's 6.4 TB/s pure-store ceiling on the same chip.
//  - dur_us decomposition: ~222us harness poison (1 GiB fill ~170us +
//    ~42us out re-poison, both outside kernel control) + ~64us kernel.
//    286us measured = exactly this sum. Remaining theoretical headroom
//    ~18us (6%); dedicated restructures (r11 persistent fill-mimic, r13
//    high-TLP) did not capture it.
//
// Structure: zero vmcnt consumers after the prologue —
//  - W[h][:,k] in 64 registers per lane (one-time load, static-indexed)
//  - wave's 32 x-rows staged once into wave-PRIVATE LDS (no barriers ever)
//  - lt[i][k] lives in lane k's register; gather via __shfl (lgkmcnt only)
//  - buckets computed arithmetically: for alpha=1.9 beta=3.8 gamma=15.2,
//    pidx(d) = sign(d)*q(|d|), q = {0,1,2,2,3,3,...} (verified bit-exact
//    vs the rp_bucket table since r6; absmax 0.0 on every round)
//  - stores are fire-and-forget until end-of-kernel drain.
// GEMV keeps the exact d-ascending fmaf chain -> bit-identical output.

constexpr int cL = 1024;
constexpr int cD = 64;
constexpr int cK = 49;
constexpr int cRW = 32;   // rows per wave

typedef float vf4 __attribute__((ext_vector_type(4)));

// piecewise_index(d) + BETA_INT for this config (verified absmax 0.0)
__device__ __forceinline__ int bucket_c(int d) {
    int a = d < 0 ? -d : d;
    int m = a < 4 ? a : 4;     // min(|d|,4)
    m -= (m >= 3) ? 1 : 0;     // q(|d|) = {0,1,2,2,3,3,...}
    int p = d < 0 ? -m : m;    // sign(d)*q
    return p + 3;              // + BETA_INT
}

__global__ __launch_bounds__(256) void irpe_wavestream(
    const float* __restrict__ x,   // (bh, i, d)
    const float* __restrict__ W,   // (h, d, k)
    float*       __restrict__ out) // (bh, i, j)
{
    __shared__ float xw[4][cRW * cD];    // 4 waves x 8 KB, wave-private

    const int gid  = blockIdx.x;         // 512 blocks = 2/CU
    const int bh   = gid & 63;
    const int segq = gid >> 6;           // 0..7
    const int tid  = threadIdx.x;
    const int w    = tid >> 6;           // wave 0..3
    const int lane = tid & 63;
    const int i0w  = segq * 128 + w * cRW;
    const int h    = bh & 7;

    // ---- one-time: this lane's W column into registers ----
    const int klane = lane < cK ? lane : lane - cK;   // lanes 49-63: dup k
    float wreg[cD];
    const float* wcol = W + (size_t)h * cD * cK + klane;
    #pragma unroll
    for (int d = 0; d < cD; ++d) wreg[d] = wcol[(size_t)d * cK];

    // ---- one-time: stage this wave's 32 x-rows into its LDS region ----
    vf4*       xw4  = (vf4*)xw[w];
    const vf4* xsrc = (const vf4*)(x + ((size_t)bh * cL + i0w) * cD);
    #pragma unroll
    for (int r = 0; r < 8; ++r) xw4[r * 64 + lane] = xsrc[r * 64 + lane];
    // (same wave writes & reads its region: lgkmcnt ordering, no barrier)

    // per-lane store-side constants
    const int xj = (lane * 4) & 31;      // (lane*4+cc)&31 = xj+cc, cc<4
    const int l8 = lane >> 3;            // yj = s*8 + l8

    const float* xrow  = xw[w];
    vf4*         obase = (vf4*)(out + ((size_t)bh * cL + i0w) * cL);

    for (int rp = 0; rp < cRW; rp += 2) {
        // GEMV rows rp, rp+1: two interleaved serial chains, d ascending
        // (exact fmaf order of all prior rounds -> bit-identical lt)
        float a0 = 0.0f, a1 = 0.0f;
        const vf4* xr0 = (const vf4*)(xrow + (rp + 0) * cD);
        const vf4* xr1 = (const vf4*)(xrow + (rp + 1) * cD);
        #pragma unroll
        for (int dq = 0; dq < cD / 4; ++dq) {
            vf4 v0 = xr0[dq];            // all lanes same addr: broadcast
            vf4 v1 = xr1[dq];
            #pragma unroll
            for (int u = 0; u < 4; ++u) {
                a0 = fmaf(v0[u], wreg[dq * 4 + u], a0);
                a1 = fmaf(v1[u], wreg[dq * 4 + u], a1);
            }
        }
        // gather (register shuffle) + 8 fire-and-forget stores
        #pragma unroll
        for (int rr = 0; rr < 2; ++rr) {
            const int   i   = i0w + rp + rr;
            const float acc = rr ? a1 : a0;
            const int   yi  = i >> 5;
            const int   xi  = i & 31;
            const int   bse = xi - xj;
            int cb[4];
            #pragma unroll
            for (int cc = 0; cc < 4; ++cc) cb[cc] = bucket_c(bse - cc);
            #pragma unroll
            for (int s = 0; s < 4; ++s) {
                const int rb = 7 * bucket_c(yi - (s * 8 + l8));
                vf4 o;
                o.x = __shfl(acc, rb + cb[0], 64);
                o.y = __shfl(acc, rb + cb[1], 64);
                o.z = __shfl(acc, rb + cb[2], 64);
                o.w = __shfl(acc, rb + cb[3], 64);
                obase[(size_t)(rp + rr) * (cL / 4) + s * 64 + lane] = o;
            }
        }
    }
}

extern "C" void kernel_launch(void* const* d_in, const int* in_sizes, int n_in,
                              void* d_out, int out_size, void* d_ws, size_t ws_size,
                              hipStream_t stream) {
    const float* x   = (const float*)d_in[0];   // (8,8,1024,64) fp32
    const float* W   = (const float*)d_in[1];   // (8,64,49) fp32
    float*       out = (float*)d_out;           // (8,8,1024,1024) fp32

    const int grid = 64 * 8;                    // 512 blocks, 2 per CU
    irpe_wavestream<<<grid, 256, 0, stream>>>(x, W, out);
}